// Round 1
// 1258.561 us; speedup vs baseline: 1.0797x; 1.0797x over previous
//
#include <hip/hip_runtime.h>
#include <hip/hip_fp16.h>
#include <math.h>

#define HW_ (512 * 512)

__device__ inline float2 cadd(float2 a, float2 b){ return make_float2(a.x+b.x, a.y+b.y); }
__device__ inline float2 csub(float2 a, float2 b){ return make_float2(a.x-b.x, a.y-b.y); }
__device__ inline float2 cmulf(float2 a, float2 b){ return make_float2(a.x*b.x-a.y*b.y, a.x*b.y+a.y*b.x); }
__device__ inline float bf2f(unsigned short u){ return __uint_as_float(((unsigned int)u) << 16); }
__device__ inline unsigned short f2bf(float f){
    unsigned int x = __float_as_uint(f);
    x += 0x7fffu + ((x >> 16) & 1u);
    return (unsigned short)(x >> 16);
}

// ---------- 8-point DFT in registers, natural-order output ----------
template<bool INV>
__device__ inline void dft8(const float2 a[8], float2 X[8]) {
    const float C = 0.70710678118654752440f;
    float2 t0 = cadd(a[0], a[4]), t4 = csub(a[0], a[4]);
    float2 t1 = cadd(a[1], a[5]), d1 = csub(a[1], a[5]);
    float2 t2 = cadd(a[2], a[6]), d2 = csub(a[2], a[6]);
    float2 t3 = cadd(a[3], a[7]), d3 = csub(a[3], a[7]);
    float2 t5, t6, t7;
    if (!INV) {
        t5 = make_float2(C*(d1.x + d1.y), C*(d1.y - d1.x));   // * (C,-C)
        t6 = make_float2(d2.y, -d2.x);                        // * -i
        t7 = make_float2(C*(d3.y - d3.x), -C*(d3.x + d3.y));  // * (-C,-C)
    } else {
        t5 = make_float2(C*(d1.x - d1.y), C*(d1.y + d1.x));   // * (C,C)
        t6 = make_float2(-d2.y, d2.x);                        // * +i
        t7 = make_float2(-C*(d3.x + d3.y), C*(d3.x - d3.y));  // * (-C,C)
    }
    float2 u0 = cadd(t0, t2), u2 = csub(t0, t2);
    float2 u1 = cadd(t1, t3), e3 = csub(t1, t3);
    float2 u3 = INV ? make_float2(-e3.y, e3.x) : make_float2(e3.y, -e3.x);
    float2 u4 = cadd(t4, t6), u6 = csub(t4, t6);
    float2 u5 = cadd(t5, t7), e7 = csub(t5, t7);
    float2 u7 = INV ? make_float2(-e7.y, e7.x) : make_float2(e7.y, -e7.x);
    X[0] = cadd(u0, u1); X[4] = csub(u0, u1);
    X[2] = cadd(u2, u3); X[6] = csub(u2, u3);
    X[1] = cadd(u4, u5); X[5] = csub(u4, u5);
    X[3] = cadd(u6, u7); X[7] = csub(u6, u7);
}

// ---------- 512-pt FFT: radix-8^3 Stockham, registers + 2 LDS exchanges ----------
// Entry: a[j] = x[lane + 64*j].  Exit: a[k] = X[lane + 64*k] (natural order).
// xch: 576-float2 wave-private LDS region. T1/T2 are FORWARD twiddle bases
// exp(-2pi i lane/512), exp(-2pi i (lane>>3)/64); conjugated internally if INV.
template<bool INV>
__device__ inline void fft512_reg(float2 a[8], float2* __restrict__ xch,
                                  int lane, float2 T1, float2 T2)
{
    float2 tw1 = INV ? make_float2(T1.x, -T1.y) : T1;
    float2 tw2 = INV ? make_float2(T2.x, -T2.y) : T2;
    const int rdo = lane + (lane >> 3);        // read offset base (skewed)
    float2 b[8];

    // stage 1: n=512, s=1, p=lane
    dft8<INV>(a, b);
    { float2 w = tw1;
      #pragma unroll
      for (int k = 1; k < 8; ++k) { b[k] = cmulf(b[k], w); w = cmulf(w, tw1); } }
    #pragma unroll
    for (int k = 0; k < 8; ++k) xch[9*lane + k] = b[k];   // e=8t+k -> e+(e>>3)
    __asm__ volatile("s_waitcnt lgkmcnt(0)" ::: "memory");
    #pragma unroll
    for (int j = 0; j < 8; ++j) a[j] = xch[rdo + 72*j];   // e=t+64j

    // stage 2: n=64, s=8, p=lane>>3, q=lane&7
    dft8<INV>(a, b);
    { float2 w = tw2;
      #pragma unroll
      for (int k = 1; k < 8; ++k) { b[k] = cmulf(b[k], w); w = cmulf(w, tw2); } }
    { const int wbase = (lane & 7) + 72 * (lane >> 3);    // e=q+64p+8k -> q+72p+9k
      #pragma unroll
      for (int k = 0; k < 8; ++k) xch[wbase + 9*k] = b[k]; }
    __asm__ volatile("s_waitcnt lgkmcnt(0)" ::: "memory");
    #pragma unroll
    for (int j = 0; j < 8; ++j) b[j] = xch[rdo + 72*j];

    // stage 3: n=8, s=64, p=0 (no twiddle), output natural order
    dft8<INV>(b, a);
}

// ---------- constants: propT/greenT/MT in TRANSPOSED [w][h] layout ----------
__global__ __launch_bounds__(256)
void k_pre(const float* __restrict__ kz, const float* __restrict__ otfa,
           const float* __restrict__ gmask, const float* __restrict__ otfp,
           float2* __restrict__ propT, float2* __restrict__ greenT,
           float2* __restrict__ MT)
{
    __shared__ float2 tp[32*33], tg[32*33], tm[32*33];
    const int tid = threadIdx.x;
    const int w0 = (blockIdx.x & 15) << 5;
    const int h0 = (blockIdx.x >> 4) << 5;
    const int ww = tid & 31, hh = tid >> 5;   // hh 0..7
    #pragma unroll
    for (int p = 0; p < 4; ++p) {
        int h = hh + p*8;
        int idx = (h0 + h)*512 + w0 + ww;
        float k = kz[idx];
        float sn, cs; __sincosf(k * 0.1f, &sn, &cs);
        float inv2 = 0.5f / k * gmask[idx];
        float phase = otfp[idx] - k * 0.5f;     // otfp + kz*DZ*(20-25)
        float s2, c2; __sincosf(phase, &s2, &c2);
        float oa = otfa[idx];
        tp[h*33 + ww] = make_float2(cs, sn);
        tg[h*33 + ww] = make_float2(-sn*inv2, cs*inv2);
        tm[h*33 + ww] = make_float2(oa*c2, oa*s2);
    }
    __syncthreads();
    #pragma unroll
    for (int p = 0; p < 4; ++p) {
        int wrow = hh + p*8;
        size_t o = (size_t)(w0 + wrow)*512 + h0 + ww;
        propT[o]  = tp[ww*33 + wrow];
        greenT[o] = tg[ww*33 + wrow];
        MT[o]     = tm[ww*33 + wrow];
    }
}

// ---------- sample [B,H,W,S] f32 -> sampT [S,B,H,W] bf16 complex ----------
// One 128-w chunk per block (8192 blocks).  float4 loads, XOR-swizzled LDS
// (write conflicts ~1.3-way, reads conflict-free b128), uint4 stores.
__global__ __launch_bounds__(256)
void k_transpose(const float* __restrict__ sre, const float* __restrict__ sim,
                 ushort2* __restrict__ sampT)
{
    __shared__ __align__(16) ushort2 tile[40 * 128];
    const int bh = blockIdx.x >> 2;          // b*512 + h
    const int chunk = blockIdx.x & 3;
    const int b = bh >> 9, h = bh & 511;
    const int w0 = chunk << 7;
    const float4* sre4 = (const float4*)(sre + (size_t)bh * 20480) + chunk * 1280;
    const float4* sim4 = (const float4*)(sim + (size_t)bh * 20480) + chunk * 1280;
    #pragma unroll
    for (int i = 0; i < 5; ++i) {
        int j = threadIdx.x + (i << 8);      // 0..1279
        float4 re = sre4[j];
        float4 im = sim4[j];
        int w = j / 10;                      // w within chunk (0..127)
        int m = j - w * 10;                  // s-quad index (0..9), s = 4m+t
        // swizzle: column c = w ^ 4*(m&7); read side undoes it at quad level
        ushort2* row = &tile[(m << 2) * 128 + (w ^ ((m & 7) << 2))];
        row[0]   = make_ushort2(f2bf(re.x), f2bf(im.x));
        row[128] = make_ushort2(f2bf(re.y), f2bf(im.y));
        row[256] = make_ushort2(f2bf(re.z), f2bf(im.z));
        row[384] = make_ushort2(f2bf(re.w), f2bf(im.w));
    }
    __syncthreads();
    #pragma unroll
    for (int i = 0; i < 5; ++i) {
        int j = threadIdx.x + (i << 8);      // 0..1279
        int s = j >> 5, q = j & 31;          // s-row, w-quad
        int qp = q ^ ((s >> 2) & 7);         // undo swizzle (k = (s>>2)&7)
        uint4 v = *(const uint4*)&tile[(s << 7) + (qp << 2)];
        *(uint4*)&sampT[(((size_t)s * 4 + b) * 512 + h) * 512 + w0 + (q << 2)] = v;
    }
}

// ---------- row pass (natural layout): wave per row ----------
// mode 0: fldA = Fr(planewave)
// mode 1: fld2 = fp16( Fr( Br(fldA) * slab * DZ/512 ) )   (fldA untouched!)
// mode 2: out = |Br(fldA)|/512, cropped
__global__ __launch_bounds__(256)
void k_row(float2* __restrict__ fldA,
           ushort2* __restrict__ fld2,
           const float* __restrict__ pwre, const float* __restrict__ pwim,
           const ushort2* __restrict__ sampT,
           float* __restrict__ finout,
           int mode, int slice)
{
    __shared__ float2 xchall[4 * 576];
    const int tid = threadIdx.x, lane = tid & 63, wv = tid >> 6;
    float2* xch = &xchall[wv * 576];
    float s1, c1, s2, c2;
    __sincosf(-6.2831853071795864769f * (float)lane / 512.0f, &s1, &c1);
    __sincosf(-6.2831853071795864769f * (float)(lane >> 3) / 64.0f, &s2, &c2);
    const float2 T1 = make_float2(c1, s1), T2 = make_float2(c2, s2);

    const int r = blockIdx.x * 4 + wv;
    int b, h;
    if (mode == 2) { b = r / 448; h = 32 + (r - b * 448); }
    else           { b = r >> 9;  h = r & 511; }
    const size_t rbase = ((size_t)b * 512 + h) * 512;
    float2 a[8];

    if (mode == 0) {
        #pragma unroll
        for (int j = 0; j < 8; ++j) {
            int w = lane + (j << 6);
            a[j] = make_float2(pwre[rbase + w], pwim[rbase + w]);
        }
        fft512_reg<false>(a, xch, lane, T1, T2);
        #pragma unroll
        for (int j = 0; j < 8; ++j) fldA[rbase + lane + (j << 6)] = a[j];
        return;
    }

    #pragma unroll
    for (int j = 0; j < 8; ++j) a[j] = fldA[rbase + lane + (j << 6)];
    fft512_reg<true>(a, xch, lane, T1, T2);    // unnormalized Br

    if (mode == 2) {
        float* orow = finout + ((size_t)b * 448 + (h - 32)) * 448;
        #pragma unroll
        for (int j = 0; j < 8; ++j) {
            int w = lane + (j << 6);
            if (w >= 32 && w < 480) {
                float2 v = a[j];
                orow[w - 32] = sqrtf(v.x*v.x + v.y*v.y) * (1.0f / 512.0f);
            }
        }
        return;
    }

    const float scale = 0.1f / 512.0f;         // DZ * (1/512 column-inverse norm)
    const size_t sbase = (((size_t)slice * 4 + b) * 512 + h) * 512;
    #pragma unroll
    for (int j = 0; j < 8; ++j) {
        int w = lane + (j << 6);
        ushort2 u = sampT[sbase + w];
        float sr = bf2f(u.x), si = bf2f(u.y);
        float2 v = a[j];
        a[j] = make_float2((v.x*sr - v.y*si) * scale, (v.x*si + v.y*sr) * scale);
    }
    fft512_reg<false>(a, xch, lane, T1, T2);
    #pragma unroll
    for (int j = 0; j < 8; ++j) {
        float2 v = a[j];
        fld2[rbase + lane + (j << 6)] =
            make_ushort2(__half_as_ushort(__float2half(v.x)),
                         __half_as_ushort(__float2half(v.y)));
    }
}

// ---------- column pass: 8 columns/block, wave per column ----------
// No incT: inc is recomputed as Fc(fldA) (fldA holds Bc(inc)/512 invariantly).
//   inc = Fc(fldA); s5 = Fc(fld2); nw = prop*inc + green*s5 (last: *= M);
//   fldA = Bc(nw)/512.
__global__ __launch_bounds__(512)
void k_col(float2* __restrict__ fldA,
           const ushort2* __restrict__ fld2,
           const float2* __restrict__ propT, const float2* __restrict__ greenT,
           const float2* __restrict__ MT, int last)
{
    __shared__ float2 tileA[512 * 9];          // fldA tile; then 8 xch regions; then out
    __shared__ ushort2 tile2[512 * 9];         // fld2 tile (fp16 pairs)
    const int tid = threadIdx.x;
    const int lane = tid & 63, wv = tid >> 6;  // wv 0..7
    const int b = blockIdx.x >> 6;
    const int w0 = (blockIdx.x & 63) << 3;
    const int c = tid & 7, hb = tid >> 3;      // cooperative load mapping
    const size_t gbase = (size_t)b * HW_ + w0;

    float s1, c1, s2, c2;
    __sincosf(-6.2831853071795864769f * (float)lane / 512.0f, &s1, &c1);
    __sincosf(-6.2831853071795864769f * (float)(lane >> 3) / 64.0f, &s2, &c2);
    const float2 T1 = make_float2(c1, s1), T2 = make_float2(c2, s2);

    #pragma unroll
    for (int j = 0; j < 8; ++j) {
        int h = hb + (j << 6);
        tileA[h*9 + c] = fldA[gbase + (size_t)h * 512 + c];
        tile2[h*9 + c] = fld2[gbase + (size_t)h * 512 + c];
    }
    __syncthreads();
    float2 aA[8], aS[8];
    #pragma unroll
    for (int j = 0; j < 8; ++j) {
        int idx = (lane + (j << 6)) * 9 + wv;
        aA[j] = tileA[idx];
        ushort2 u = tile2[idx];
        aS[j] = make_float2(__half2float(__ushort_as_half(u.x)),
                            __half2float(__ushort_as_half(u.y)));
    }
    __syncthreads();                            // tileA dead; becomes xch regions
    float2* xch = &tileA[wv * 576];

    fft512_reg<false>(aA, xch, lane, T1, T2);   // inc
    fft512_reg<false>(aS, xch, lane, T1, T2);   // s5

    const int w = w0 + wv;
    const size_t pbase = (size_t)w * 512;
    #pragma unroll
    for (int k = 0; k < 8; ++k) {
        int h = lane + (k << 6);
        float2 p  = propT[pbase + h];
        float2 g  = greenT[pbase + h];
        float2 nw = make_float2(p.x*aA[k].x - p.y*aA[k].y + g.x*aS[k].x - g.y*aS[k].y,
                                p.x*aA[k].y + p.y*aA[k].x + g.x*aS[k].y + g.y*aS[k].x);
        if (last) nw = cmulf(nw, MT[pbase + h]);
        aA[k] = nw;
    }

    fft512_reg<true>(aA, xch, lane, T1, T2);    // Bc, unnormalized
    __syncthreads();                            // all waves done with xch
    const float inv = 1.0f / 512.0f;
    #pragma unroll
    for (int k = 0; k < 8; ++k)
        tileA[(lane + (k << 6)) * 9 + wv] = make_float2(aA[k].x * inv, aA[k].y * inv);
    __syncthreads();
    #pragma unroll
    for (int j = 0; j < 8; ++j) {
        int h = hb + (j << 6);
        fldA[gbase + (size_t)h * 512 + c] = tileA[h*9 + c];
    }
}

extern "C" void kernel_launch(void* const* d_in, const int* in_sizes, int n_in,
                              void* d_out, int out_size, void* d_ws, size_t ws_size,
                              hipStream_t stream)
{
    (void)in_sizes; (void)n_in; (void)out_size; (void)ws_size;
    const float* sre   = (const float*)d_in[0];
    const float* simg  = (const float*)d_in[1];
    const float* pwre  = (const float*)d_in[2];
    const float* pwim  = (const float*)d_in[3];
    const float* kz    = (const float*)d_in[4];
    const float* otfa  = (const float*)d_in[5];
    const float* gmask = (const float*)d_in[6];
    const float* otfp  = (const float*)d_in[7];

    char* ws = (char*)d_ws;
    size_t off = 0;
    float2* propT  = (float2*)(ws + off); off += (size_t)HW_ * 8;
    float2* greenT = (float2*)(ws + off); off += (size_t)HW_ * 8;
    float2* MT     = (float2*)(ws + off); off += (size_t)HW_ * 8;
    float2* fldA   = (float2*)(ws + off); off += (size_t)4 * HW_ * 8;
    ushort2* fld2  = (ushort2*)(ws + off); off += (size_t)4 * HW_ * 4;
    ushort2* sampT = (ushort2*)(ws + off);

    k_pre<<<256, 256, 0, stream>>>(kz, otfa, gmask, otfp, propT, greenT, MT);
    k_transpose<<<8192, 256, 0, stream>>>(sre, simg, sampT);

    // fldA = Fr(planewave).  Invariant: fldA == Bc(inc)/512 since
    // Bc(Fc(Fr(pw)))/512 == Fr(pw) -- no init column pass needed.
    k_row<<<512, 256, 0, stream>>>(fldA, nullptr, pwre, pwim, nullptr, nullptr, 0, 0);

    for (int s = 0; s < 40; ++s) {
        k_row<<<512, 256, 0, stream>>>(fldA, fld2, nullptr, nullptr, sampT, nullptr, 1, s);
        k_col<<<256, 512, 0, stream>>>(fldA, fld2, propT, greenT, MT, (s == 39) ? 1 : 0);
    }
    // out = |Br(fldA)|/512, rows 32..479, cols 32..479
    k_row<<<448, 256, 0, stream>>>(fldA, nullptr, nullptr, nullptr, nullptr, (float*)d_out, 2, 0);
}